// Round 1
// baseline (751.065 us; speedup 1.0000x reference)
//
#include <hip/hip_runtime.h>
#include <hip/hip_bf16.h>

#define DEV __device__ __forceinline__

typedef __attribute__((ext_vector_type(8))) short bf16x8;
typedef __attribute__((ext_vector_type(4))) float f32x4;

static constexpr int Bsz = 64, S = 256, H = 1024, E = 512, ENCD = 1024, V = 32000;

DEV unsigned short f2bf(float f) {
    unsigned u = __builtin_bit_cast(unsigned, f);
    unsigned r = (u + 0x7FFFu + ((u >> 16) & 1u)) >> 16;
    return (unsigned short)r;
}
DEV float sigmoidf_(float x) { return 1.0f / (1.0f + __expf(-x)); }

// ---------------------------------------------------------------------------
// prep: embedding gather + bf16 casts of hidden0/hidden1/embedded into the
// concatenated A matrices.
// A0  = [emb(512) | ctx(1024) | hidden0(1024)]  (64 x 2560 bf16)
// A1  = [h0(1024) | hidden1(1024)]              (64 x 2048 bf16)
// FEAT= [h1(1024) | ctx(1024)   | emb(512)]     (64 x 2560 bf16)
// ---------------------------------------------------------------------------
__global__ void prep_kernel(const int* __restrict__ tok, const float* __restrict__ hidden,
                            const float* __restrict__ emb,
                            unsigned short* __restrict__ A0, unsigned short* __restrict__ A1,
                            unsigned short* __restrict__ FEAT) {
    int b = blockIdx.x, t = threadIdx.x;
    int tb = tok[b];
    for (int c = t; c < E; c += 256) {
        unsigned short us = f2bf(emb[(size_t)tb * E + c]);
        A0[b * 2560 + c] = us;            // x0 head
        FEAT[b * 2560 + 2048 + c] = us;   // feat tail
    }
    for (int c = t; c < H; c += 256) {
        A0[b * 2560 + 1536 + c] = f2bf(hidden[b * H + c]);              // hidden[0]
        A1[b * 2048 + 1024 + c] = f2bf(hidden[Bsz * H + b * H + c]);    // hidden[1]
    }
}

// ---------------------------------------------------------------------------
// keys GEMM (16384x1024x1024 bf16 MFMA) with fused energy epilogue:
//   energy[row] += sum_h v[h] * tanh(keys[row][h] + query[b][h])
// 128x128 tile, 4 waves, single-buffered LDS (padded +8 bf16 per row).
// ---------------------------------------------------------------------------
__global__ __launch_bounds__(256) void keys_energy_kernel(
        const float* __restrict__ enc, const float* __restrict__ Wk,
        const float* __restrict__ query, const float* __restrict__ vvec,
        float* __restrict__ energy) {
    __shared__ __align__(16) unsigned short At[128 * 40];
    __shared__ __align__(16) unsigned short Bt[128 * 40];

    int blk = blockIdx.x;
    int xcd = blk & 7, idx = blk >> 3;
    int bn = idx & 7, bml = idx >> 3;
    int bm = xcd * 16 + bml;              // 128 row-blocks, 8 col-blocks
    int rm0 = bm * 128, n0 = bn * 128;

    int t = threadIdx.x;
    int lane = t & 63, w = t >> 6;
    int l15 = lane & 15, lg = lane >> 4;
    int r = t >> 1, seg = t & 1;          // staging: 2 threads per row, 16 elems each
    int wrow = (w >> 1) * 64, wcol = (w & 1) * 64;

    const float* Ag = enc + (size_t)(rm0 + r) * ENCD + seg * 16;
    const float* Bg = Wk  + (size_t)(n0  + r) * ENCD + seg * 16;

    f32x4 acc[4][4];
#pragma unroll
    for (int m = 0; m < 4; ++m)
#pragma unroll
        for (int n = 0; n < 4; ++n) acc[m][n] = (f32x4)0.0f;

    for (int kk = 0; kk < 32; ++kk) {
        int k0 = kk * 32;
        float4 a0 = *(const float4*)(Ag + k0);
        float4 a1 = *(const float4*)(Ag + k0 + 4);
        float4 a2 = *(const float4*)(Ag + k0 + 8);
        float4 a3 = *(const float4*)(Ag + k0 + 12);
        float4 b0 = *(const float4*)(Bg + k0);
        float4 b1 = *(const float4*)(Bg + k0 + 4);
        float4 b2 = *(const float4*)(Bg + k0 + 8);
        float4 b3 = *(const float4*)(Bg + k0 + 12);

        bf16x8 pa0, pa1, pb0, pb1;
        pa0[0]=f2bf(a0.x); pa0[1]=f2bf(a0.y); pa0[2]=f2bf(a0.z); pa0[3]=f2bf(a0.w);
        pa0[4]=f2bf(a1.x); pa0[5]=f2bf(a1.y); pa0[6]=f2bf(a1.z); pa0[7]=f2bf(a1.w);
        pa1[0]=f2bf(a2.x); pa1[1]=f2bf(a2.y); pa1[2]=f2bf(a2.z); pa1[3]=f2bf(a2.w);
        pa1[4]=f2bf(a3.x); pa1[5]=f2bf(a3.y); pa1[6]=f2bf(a3.z); pa1[7]=f2bf(a3.w);
        pb0[0]=f2bf(b0.x); pb0[1]=f2bf(b0.y); pb0[2]=f2bf(b0.z); pb0[3]=f2bf(b0.w);
        pb0[4]=f2bf(b1.x); pb0[5]=f2bf(b1.y); pb0[6]=f2bf(b1.z); pb0[7]=f2bf(b1.w);
        pb1[0]=f2bf(b2.x); pb1[1]=f2bf(b2.y); pb1[2]=f2bf(b2.z); pb1[3]=f2bf(b2.w);
        pb1[4]=f2bf(b3.x); pb1[5]=f2bf(b3.y); pb1[6]=f2bf(b3.z); pb1[7]=f2bf(b3.w);

        __syncthreads();   // previous tile fully consumed
        *(bf16x8*)&At[r * 40 + seg * 16]     = pa0;
        *(bf16x8*)&At[r * 40 + seg * 16 + 8] = pa1;
        *(bf16x8*)&Bt[r * 40 + seg * 16]     = pb0;
        *(bf16x8*)&Bt[r * 40 + seg * 16 + 8] = pb1;
        __syncthreads();

        bf16x8 af[4], bfv[4];
#pragma unroll
        for (int m = 0; m < 4; ++m)
            af[m] = *(const bf16x8*)&At[(wrow + m * 16 + l15) * 40 + lg * 8];
#pragma unroll
        for (int n = 0; n < 4; ++n)
            bfv[n] = *(const bf16x8*)&Bt[(wcol + n * 16 + l15) * 40 + lg * 8];
#pragma unroll
        for (int m = 0; m < 4; ++m)
#pragma unroll
            for (int n = 0; n < 4; ++n)
                acc[m][n] = __builtin_amdgcn_mfma_f32_16x16x32_bf16(af[m], bfv[n], acc[m][n], 0, 0, 0);
    }

    // epilogue: energy[row] += sum_cols v[c]*tanh(acc + query[b][c])
    int b = rm0 >> 8;                      // S = 256, 128-row block lies in one b
    const float* qrow = query + b * H;
#pragma unroll
    for (int m = 0; m < 4; ++m) {
#pragma unroll
        for (int j = 0; j < 4; ++j) {
            int gr = rm0 + wrow + m * 16 + lg * 4 + j;
            float part = 0.f;
#pragma unroll
            for (int nf = 0; nf < 4; ++nf) {
                int gc = n0 + wcol + nf * 16 + l15;
                float val = acc[m][nf][j] + qrow[gc];
                part += vvec[gc] * tanhf(val);
            }
            part += __shfl_xor(part, 1);
            part += __shfl_xor(part, 2);
            part += __shfl_xor(part, 4);
            part += __shfl_xor(part, 8);
            if (l15 == 0) atomicAdd(&energy[gr], part);
        }
    }
}

// ---------------------------------------------------------------------------
// masked softmax over S=256 + context = attn @ enc. grid = 64 b * 4 col-quads.
// ---------------------------------------------------------------------------
__global__ void softmax_ctx_kernel(const float* __restrict__ energy, const int* __restrict__ mask,
                                   const float* __restrict__ enc, float* __restrict__ attn_out,
                                   unsigned short* __restrict__ A0, unsigned short* __restrict__ FEAT) {
    int b = blockIdx.x >> 2, cq = blockIdx.x & 3;
    int t = threadIdx.x;
    __shared__ float wsm[256];
    __shared__ float red[256];

    float e = energy[b * S + t];
    if (mask[b * S + t] == 0) e = -1e10f;
    red[t] = e; __syncthreads();
    for (int o = 128; o > 0; o >>= 1) { if (t < o) red[t] = fmaxf(red[t], red[t + o]); __syncthreads(); }
    float mx = red[0]; __syncthreads();
    float ex = __expf(e - mx);
    red[t] = ex; __syncthreads();
    for (int o = 128; o > 0; o >>= 1) { if (t < o) red[t] += red[t + o]; __syncthreads(); }
    float sum = red[0];
    float wt = ex / sum;
    wsm[t] = wt;
    if (cq == 0) attn_out[b * S + t] = wt;
    __syncthreads();

    int c = cq * 256 + t;
    float acc = 0.f;
    for (int s = 0; s < S; ++s) acc += wsm[s] * enc[((size_t)b * S + s) * ENCD + c];
    unsigned short us = f2bf(acc);
    A0[b * 2560 + 512 + c] = us;      // x0 ctx
    FEAT[b * 2560 + 1024 + c] = us;   // feat ctx
}

// ---------------------------------------------------------------------------
// generic skinny GEMM: C[64][N] = A_bf16[64][K1+K2] @ [W1|W2]^T (+b1+b2)
// NT cols per block, 4 waves split K, MFMA 16x16x32, LDS cross-wave reduce.
// W rows are f32, converted to bf16 in-register.
// ---------------------------------------------------------------------------
template <int NT>
__global__ __launch_bounds__(256) void gemm_skinny_kernel(
        const unsigned short* __restrict__ A, int lda,
        const float* __restrict__ W1, int K1,
        const float* __restrict__ W2, int K2,
        const float* __restrict__ b1, const float* __restrict__ b2,
        float* __restrict__ C, int ldc) {
    constexpr int NF = NT / 16;
    __shared__ float red[4 * 64 * NT];

    int n0 = blockIdx.x * NT;
    int t = threadIdx.x, w = t >> 6, lane = t & 63;
    int l15 = lane & 15, lg = lane >> 4;
    int K = K1 + K2, Kw = K >> 2;
    int kbeg = w * Kw, kend = kbeg + Kw;

    f32x4 acc[4][NF];
#pragma unroll
    for (int m = 0; m < 4; ++m)
#pragma unroll
        for (int nf = 0; nf < NF; ++nf) acc[m][nf] = (f32x4)0.0f;

    for (int k0 = kbeg; k0 < kend; k0 += 32) {
        bf16x8 af[4];
#pragma unroll
        for (int m = 0; m < 4; ++m)
            af[m] = *(const bf16x8*)&A[(size_t)(m * 16 + l15) * lda + k0 + lg * 8];

#pragma unroll
        for (int nf = 0; nf < NF; ++nf) {
            int n = n0 + nf * 16 + l15;
            const float* base = (k0 < K1) ? (W1 + (size_t)n * K1 + k0 + lg * 8)
                                          : (W2 + (size_t)n * K2 + (k0 - K1) + lg * 8);
            float4 f0 = *(const float4*)base;
            float4 f1 = *(const float4*)(base + 4);
            bf16x8 bv;
            bv[0]=f2bf(f0.x); bv[1]=f2bf(f0.y); bv[2]=f2bf(f0.z); bv[3]=f2bf(f0.w);
            bv[4]=f2bf(f1.x); bv[5]=f2bf(f1.y); bv[6]=f2bf(f1.z); bv[7]=f2bf(f1.w);
#pragma unroll
            for (int m = 0; m < 4; ++m)
                acc[m][nf] = __builtin_amdgcn_mfma_f32_16x16x32_bf16(af[m], bv, acc[m][nf], 0, 0, 0);
        }
    }

    float* myred = red + w * 64 * NT;
#pragma unroll
    for (int m = 0; m < 4; ++m)
#pragma unroll
        for (int nf = 0; nf < NF; ++nf)
#pragma unroll
            for (int j = 0; j < 4; ++j)
                myred[(m * 16 + lg * 4 + j) * NT + nf * 16 + l15] = acc[m][nf][j];
    __syncthreads();

    for (int o = t; o < 64 * NT; o += 256) {
        int row = o / NT, col = o % NT;
        float s = red[o] + red[64 * NT + o] + red[2 * 64 * NT + o] + red[3 * 64 * NT + o];
        int n = n0 + col;
        if (b1) s += b1[n];
        if (b2) s += b2[n];
        C[(size_t)row * ldc + n] = s;
    }
}

// ---------------------------------------------------------------------------
// LSTM activations: gates[B][4H] (i,f,g,o) + prev cell -> h,c (f32 to d_out,
// bf16 h into the next GEMM's A matrix).
// ---------------------------------------------------------------------------
__global__ void lstm_act_kernel(const float* __restrict__ gates, const float* __restrict__ cell_in,
                                float* __restrict__ h_out, float* __restrict__ c_out,
                                unsigned short* __restrict__ hbf, int hbf_stride) {
    int b = blockIdx.x, t = threadIdx.x;
    for (int c = t; c < H; c += 256) {
        float gi = gates[b * 4096 + c];
        float gf = gates[b * 4096 + 1024 + c];
        float gg = gates[b * 4096 + 2048 + c];
        float go = gates[b * 4096 + 3072 + c];
        float cn = sigmoidf_(gf) * cell_in[b * H + c] + sigmoidf_(gi) * tanhf(gg);
        float hn = sigmoidf_(go) * tanhf(cn);
        c_out[b * H + c] = cn;
        h_out[b * H + c] = hn;
        hbf[b * hbf_stride + c] = f2bf(hn);
    }
}

// ---------------------------------------------------------------------------
extern "C" void kernel_launch(void* const* d_in, const int* in_sizes, int n_in,
                              void* d_out, int out_size, void* d_ws, size_t ws_size,
                              hipStream_t stream) {
    const int*   tok   = (const int*)d_in[0];
    const float* hidden= (const float*)d_in[1];
    const float* cell  = (const float*)d_in[2];
    const float* enc   = (const float*)d_in[3];
    const int*   mask  = (const int*)d_in[4];
    const float* emb   = (const float*)d_in[5];
    const float* Wq    = (const float*)d_in[6];
    const float* Wk    = (const float*)d_in[7];
    const float* vvec  = (const float*)d_in[8];
    const float* Wih0  = (const float*)d_in[9];
    const float* Whh0  = (const float*)d_in[10];
    const float* bih0  = (const float*)d_in[11];
    const float* bhh0  = (const float*)d_in[12];
    const float* Wih1  = (const float*)d_in[13];
    const float* Whh1  = (const float*)d_in[14];
    const float* bih1  = (const float*)d_in[15];
    const float* bhh1  = (const float*)d_in[16];
    const float* Wout  = (const float*)d_in[17];
    const float* bout  = (const float*)d_in[18];

    float* out      = (float*)d_out;
    float* pred     = out;                       // [64][32000]
    float* hid_out  = out + (size_t)Bsz * V;     // [2][64][1024]
    float* cell_out = hid_out + 2 * Bsz * H;     // [2][64][1024]
    float* attn_out = cell_out + 2 * Bsz * H;    // [64][256]

    char* ws = (char*)d_ws;
    float* query  = (float*)ws;                          // 64*1024
    float* energy = query + Bsz * H;                     // 64*256
    float* gates  = energy + Bsz * S;                    // 64*4096
    unsigned short* A0   = (unsigned short*)(gates + Bsz * 4096);  // 64*2560
    unsigned short* A1   = A0 + Bsz * 2560;                        // 64*2048
    unsigned short* FEAT = A1 + Bsz * 2048;                        // 64*2560

    hipMemsetAsync(energy, 0, (size_t)Bsz * S * sizeof(float), stream);
    prep_kernel<<<Bsz, 256, 0, stream>>>(tok, hidden, emb, A0, A1, FEAT);

    // query = hidden[1] @ Wq^T  (A = A1 cols 1024..2047)
    gemm_skinny_kernel<16><<<H / 16, 256, 0, stream>>>(
        A1 + 1024, 2048, Wq, 1024, nullptr, 0, nullptr, nullptr, query, H);

    keys_energy_kernel<<<1024, 256, 0, stream>>>(enc, Wk, query, vvec, energy);

    softmax_ctx_kernel<<<Bsz * 4, 256, 0, stream>>>(energy, mask, enc, attn_out, A0, FEAT);

    // gates0 = x0 @ Wih0^T + h_prev0 @ Whh0^T + biases
    gemm_skinny_kernel<16><<<4096 / 16, 256, 0, stream>>>(
        A0, 2560, Wih0, 1536, Whh0, 1024, bih0, bhh0, gates, 4096);
    lstm_act_kernel<<<Bsz, 256, 0, stream>>>(gates, cell, hid_out, cell_out, A1, 2048);

    // gates1 = h0 @ Wih1^T + h_prev1 @ Whh1^T + biases
    gemm_skinny_kernel<16><<<4096 / 16, 256, 0, stream>>>(
        A1, 2048, Wih1, 1024, Whh1, 1024, bih1, bhh1, gates, 4096);
    lstm_act_kernel<<<Bsz, 256, 0, stream>>>(gates, cell + Bsz * H, hid_out + Bsz * H,
                                             cell_out + Bsz * H, FEAT, 2560);

    // prediction = feat @ Wout^T + bout
    gemm_skinny_kernel<64><<<V / 64, 256, 0, stream>>>(
        FEAT, 2560, Wout, 2560, nullptr, 0, bout, nullptr, pred, V);
}